// Round 12
// baseline (2152.777 us; speedup 1.0000x reference)
//
#include <hip/hip_runtime.h>

#define LN2 0.6931471805599453f

constexpr int T = 512, N = 32, C = 4000, S = 64;
constexpr int TN   = T * N;
constexpr int ROWF = 68;          // padded pp row stride (272B, 16B-aligned)
constexpr int CT   = 8;           // timesteps per LDS chunk
constexpr int NC   = T / CT;      // 64 chunks

// ---------------- Kernel 1: row-normalized softmax probs ---------------------
// One wave per (t,n) row; REPS>1 instantiation = timing probe (scratch out).
template <int REPS>
__global__ __launch_bounds__(256) void k_softmax_probs(
    const float* __restrict__ x, const int* __restrict__ labels,
    float* __restrict__ pp, float* __restrict__ ee)
{
  for (int rep = 0; rep < REPS; ++rep) {
    if (REPS > 1) asm volatile("" ::: "memory");   // no cross-rep CSE
    int row  = blockIdx.x * 4 + (threadIdx.x >> 6);   // row = t*N + n
    int lane = threadIdx.x & 63;
    const float*  rp  = x + (size_t)row * C;
    const float4* rp4 = reinterpret_cast<const float4*>(rp);

    float m = -INFINITY, s = 0.f;
    #pragma unroll
    for (int k = 0; k < 15; ++k) {                 // 960 of 1000 float4s
        float4 v = rp4[lane + 64 * k];
        float mv = fmaxf(fmaxf(v.x, v.y), fmaxf(v.z, v.w));
        float s4 = __expf(v.x - mv) + __expf(v.y - mv) +
                   __expf(v.z - mv) + __expf(v.w - mv);
        float nm = fmaxf(m, mv);
        s = s * __expf(m - nm) + s4 * __expf(mv - nm);
        m = nm;
    }
    if (lane < 40) {                               // tail 40 float4s
        float4 v = rp4[960 + lane];
        float mv = fmaxf(fmaxf(v.x, v.y), fmaxf(v.z, v.w));
        float s4 = __expf(v.x - mv) + __expf(v.y - mv) +
                   __expf(v.z - mv) + __expf(v.w - mv);
        float nm = fmaxf(m, mv);
        s = s * __expf(m - nm) + s4 * __expf(mv - nm);
        m = nm;
    }
    for (int off = 32; off; off >>= 1) {
        float om = __shfl_xor(m, off), os = __shfl_xor(s, off);
        float nm = fmaxf(m, om);
        s = s * __expf(m - nm) + os * __expf(om - nm);
        m = nm;
    }
    float logZ = m + __logf(s);

    int t = row >> 5, n = row & 31;                // row = t*N + n, N = 32
    int c  = labels[n * S + lane];
    float zb = rp[0];                              // blank logit
    float zl = rp[c];                              // label logit

    // row max over the 65 relevant entries -> exact pow2 normalizer
    float wm = zl;
    for (int off = 32; off; off >>= 1) wm = fmaxf(wm, __shfl_xor(wm, off));
    wm = fmaxf(wm, zb);
    float pm = __expf(wm - logZ);
    int e = (int)(__float_as_uint(pm) >> 23) - 127;

    float* outp = pp + ((size_t)n * T + t) * ROWF;
    outp[1 + lane] = ldexpf(__expf(zl - logZ), -e);
    if (lane == 0) {
        outp[0] = ldexpf(__expf(zb - logZ), -e);
        ee[n * T + t] = (float)e;
    }
  }
}

// ---------------- DPP helpers ------------------------------------------------
__device__ __forceinline__ float dpp_shr1_zero(float x) {
    int r = __builtin_amdgcn_update_dpp(0, __float_as_int(x),
                                        0x138 /*wave_shr:1*/, 0xf, 0xf, false);
    return __int_as_float(r);
}
template <int CTRL>
__device__ __forceinline__ float dpp_max_step(float x) {
    int t = __builtin_amdgcn_update_dpp(__float_as_int(x), __float_as_int(x),
                                        CTRL, 0xf, 0xf, false);
    return fmaxf(x, __int_as_float(t));
}
__device__ __forceinline__ float wave_max_bcast(float x) {
    x = dpp_max_step<0xB1>(x);    // xor 1
    x = dpp_max_step<0x4E>(x);    // xor 2
    x = dpp_max_step<0x141>(x);   // xor 4
    x = dpp_max_step<0x140>(x);   // xor 8
    x = dpp_max_step<0x142>(x);   // row_bcast15
    x = dpp_max_step<0x143>(x);   // row_bcast31
    return __int_as_float(__builtin_amdgcn_readlane(__float_as_int(x), 63));
}

// ---------------- Kernel 2: alpha recursion ---------------------------------
// 2 blocks x 16 waves: all 32 chains co-located at 4 waves/SIMD so the SIMD
// interleaves independent chains and hides per-wave dependency stalls.
// Algorithm identical to R11 (pair-composed steps, lag-2 off-chain renorm).
template <int REPS>
__global__ __launch_bounds__(1024) void k_ctc_alpha(
    const float* __restrict__ pp, const float* __restrict__ ee,
    const int* __restrict__ labels,
    const int* __restrict__ input_len, const int* __restrict__ label_len,
    float* __restrict__ loss_out)
{
    __shared__ __align__(16) float lds[16][2][CT][ROWF];   // 69.6 KB
    const int wid = threadIdx.x >> 6, lane = threadIdx.x & 63;
    const int n = blockIdx.x * 16 + wid;
    float (*ldsw)[CT][ROWF] = lds[wid];
    const int Tin = input_len[n], Sl = label_len[n];
    const float* bp = pp + (size_t)n * T * ROWF;

    const int li   = labels[n * S + lane];
    const int lim1 = lane ? labels[n * S + lane - 1] : -1;
    const float skf  = (lane > 0 && li != 0 && li != lim1) ? 1.f : 0.f;
    const float skUf = dpp_shr1_zero(skf);
    const float skk  = skf * skUf;

#define ISSUE(cc) do {                                                        \
    const float* cp_ = bp + (size_t)(cc) * CT * ROWF;                         \
    if (lane < 17) {                                                          \
        _Pragma("unroll")                                                     \
        for (int d_ = 0; d_ < CT; ++d_)                                       \
            __builtin_amdgcn_global_load_lds(cp_ + (size_t)d_ * ROWF + lane * 4, \
                                             &ldsw[(cc) & 1][d_][0], 16, 0, 0);\
    } } while (0)

// two composed timesteps (coefficients off-chain; alpha chain = 3 dpp + fma tree)
#define PAIRS(B, D) do {                                                      \
    const float* R0_ = &ldsw[B][D][0];                                        \
    const float* R1_ = &ldsw[B][(D) + 1][0];                                  \
    float cb1 = R0_[0], cl1 = R0_[1 + lane];                                  \
    float cb2 = R1_[0], cl2 = R1_[1 + lane];                                  \
    float clU = dpp_shr1_zero(cl1);                                           \
    float W   = clU * cl2;                                                    \
    float A   = cb1 * cb2;                                                    \
    float B_  = clU * cb2;                                                    \
    float Cc  = A + B_;                                                       \
    float D_  = skUf * B_;                                                    \
    float s1  = cb1 + cl1;                                                    \
    float E   = s1 * cl2;                                                     \
    float F   = cl1 * cl2;                                                    \
    float G   = skf * W;                                                      \
    float H   = fmaf(skf, F + W, cb1 * cl2);                                  \
    float I   = skk * W;                                                      \
    float Y0  = cl1 * cb2;                                                    \
    float Y1  = s1 * cb2;                                                     \
    float Y2  = skf * Y0;                                                     \
    float p1  = dpp_shr1_zero(a1);                                            \
    float p0  = dpp_shr1_zero(a0);                                            \
    float p2  = dpp_shr1_zero(p1);                                            \
    float n0  = fmaf(p0, B_, a0 * A) + fmaf(p2, D_, p1 * Cc);                 \
    float n1  = fmaf(a1, F, a0 * E) + fmaf(p2, I, fmaf(p1, H, p0 * G));       \
    float nX  = fmaf(a1, Y1, aX * A) + fmaf(p1, Y2, a0 * Y0);                 \
    a0 = n0; a1 = n1; aX = nX;                                                \
} while (0)

// 8-step window: apply kA (lag-2 snapshot), fresh snapshot, 4 pairs with the
// previous snapshot's max-tree interleaved off-chain.
#define WINDOW4(B, D0) do {                                                   \
    a0 = ldexpf(a0, kA); a1 = ldexpf(a1, kA); aX = ldexpf(aX, kA);            \
    SH += kA;                                                                 \
    float gnow_ = fmaxf(fmaxf(a0, a1), aX);                                   \
    PAIRS(B, D0);                                                             \
    gs = dpp_max_step<0xB1>(gs);  gs = dpp_max_step<0x4E>(gs);                \
    PAIRS(B, (D0) + 2);                                                       \
    gs = dpp_max_step<0x141>(gs); gs = dpp_max_step<0x140>(gs);               \
    PAIRS(B, (D0) + 4);                                                       \
    gs = dpp_max_step<0x142>(gs); gs = dpp_max_step<0x143>(gs);               \
    PAIRS(B, (D0) + 6);                                                       \
    {   unsigned b_ = (unsigned)__builtin_amdgcn_readlane(__float_as_int(gs), 63); \
        int e_ = (int)(b_ >> 23) - 127;                                       \
        kA = (b_ == 0u) ? 0 : (105 - e_ - kA);                                \
    }                                                                         \
    gs = gnow_;                                                               \
} while (0)

  for (int rep = 0; rep < REPS; ++rep) {
    if (REPS > 1) asm volatile("" ::: "memory");   // no cross-rep CSE
    asm volatile("s_waitcnt vmcnt(0)" ::: "memory");   // exact DMA counting
    __builtin_amdgcn_sched_barrier(0);

    float a0 = 0.f, a1 = 0.f, aX = 0.f;
    int SH = 0, kA = 0;
    float gs = 0.f;

    if (Tin == T) {
        // ---------------- hot path ----------------
        ISSUE(0); ISSUE(1);
        asm volatile("s_waitcnt vmcnt(8)" ::: "memory");   // chunk 0 landed
        __builtin_amdgcn_sched_barrier(0);
        a0 = (lane == 0) ? ldsw[0][0][0] : 0.f;
        a1 = (lane == 0 && Sl > 0) ? ldsw[0][0][1] : 0.f;
        {   // t = 1 single step
            float cb = ldsw[0][1][0], cl = ldsw[0][1][1 + lane];
            float p1 = dpp_shr1_zero(a1);
            float n0 = (a0 + p1) * cb;
            float n1 = fmaf(skf, p1, a0 + a1) * cl;
            float nX = (aX + a1) * cb;
            a0 = n0; a1 = n1; aX = nX;
        }
        PAIRS(0, 2); PAIRS(0, 4); PAIRS(0, 6);              // t = 2..7
        {   // direct renorm to anchor 105 (once)
            float g = wave_max_bcast(fmaxf(fmaxf(a0, a1), aX));
            unsigned b = __float_as_uint(g);
            int k0 = (b == 0u) ? 0 : (105 - ((int)(b >> 23) - 127));
            a0 = ldexpf(a0, k0); a1 = ldexpf(a1, k0); aX = ldexpf(aX, k0);
            SH += k0; kA = 0;
            gs = fmaxf(fmaxf(a0, a1), aX);
        }
        __builtin_amdgcn_sched_barrier(0);
        ISSUE(2);
        for (int c = 1; c < NC; ++c) {
            if (c < NC - 1) { asm volatile("s_waitcnt vmcnt(8)" ::: "memory"); }
            else            { asm volatile("s_waitcnt vmcnt(0)" ::: "memory"); }
            __builtin_amdgcn_sched_barrier(0);
            WINDOW4(c & 1, 0);
            if (c + 2 < NC) {
                __builtin_amdgcn_sched_barrier(0);
                ISSUE(c + 2);
            }
        }
    } else {
        // ---------------- generic fallback: per-step, freeze masking ----------
#define GSTEP(cc, dd) do {                                                    \
    float cb_ = ldsw[(cc) & 1][dd][0];                                        \
    float cl_ = ldsw[(cc) & 1][dd][1 + lane];                                 \
    float p1_ = dpp_shr1_zero(a1);                                            \
    float na0_ = (a0 + p1_) * cb_;                                            \
    float na1_ = fmaf(skf, p1_, a0 + a1) * cl_;                               \
    float naX_ = (aX + a1) * cb_;                                             \
    int t_ = (cc) * CT + (dd);                                                \
    bool act_ = (unsigned)(t_ - 1) < (unsigned)(Tin - 1);                     \
    a0 = act_ ? na0_ : a0;                                                    \
    a1 = act_ ? na1_ : a1;                                                    \
    aX = act_ ? naX_ : aX;                                                    \
    if (((dd) & 3) == 3) {                                                    \
        float g_ = wave_max_bcast(fmaxf(a0, fmaxf(a1, aX)));                  \
        unsigned b_ = __float_as_uint(g_);                                    \
        int k_ = (b_ == 0u) ? 0 : (100 - ((int)(b_ >> 23) - 127));            \
        a0 = ldexpf(a0, k_); a1 = ldexpf(a1, k_); aX = ldexpf(aX, k_);        \
        SH += k_;                                                             \
    }                                                                         \
} while (0)
        ISSUE(0); ISSUE(1);
        asm volatile("s_waitcnt vmcnt(8)" ::: "memory");
        __builtin_amdgcn_sched_barrier(0);
        a0 = (lane == 0) ? ldsw[0][0][0] : 0.f;
        a1 = (lane == 0 && Sl > 0) ? ldsw[0][0][1] : 0.f;
        #pragma unroll
        for (int d = 1; d < CT; ++d) GSTEP(0, d);
        __builtin_amdgcn_sched_barrier(0);
        ISSUE(2);
        for (int c = 1; c < NC; ++c) {
            if (c < NC - 1) { asm volatile("s_waitcnt vmcnt(8)" ::: "memory"); }
            else            { asm volatile("s_waitcnt vmcnt(0)" ::: "memory"); }
            __builtin_amdgcn_sched_barrier(0);
            #pragma unroll
            for (int d = 0; d < CT; ++d) GSTEP(c, d);
            if (c + 2 < NC) {
                __builtin_amdgcn_sched_barrier(0);
                ISSUE(c + 2);
            }
        }
#undef GSTEP
    }

    // row-scale compensation: Sigma e_t over t < Tin (off-chain, once)
    float se = 0.f;
    #pragma unroll
    for (int j = 0; j < 8; ++j) {
        int idx = lane + 64 * j;
        float ev = ee[n * T + idx];
        se += (idx < Tin) ? ev : 0.f;
    }
    for (int off = 32; off; off >>= 1) se += __shfl_xor(se, off);

    // loss_n = -log(alpha[2*Sl] + alpha[2*Sl-1]), rescaled
    float a_last = (Sl >= S) ? __shfl(aX, 63) : __shfl(a0, Sl);
    float a_prev_raw = __shfl(a1, (Sl > 0) ? (Sl - 1) : 0);
    float a_prev = (Sl > 0) ? a_prev_raw : 0.f;
    if (lane == 0) {
        float sum  = a_last + a_prev;
        float ll2  = log2f(sum) - (float)SH + se;      // log2 P
        float loss = -ll2 * LN2;
        if (!(loss < 5e29f)) loss = 0.f;               // zero_infinity (+NaN)
        loss_out[n] = loss;
    }
  }
#undef WINDOW4
#undef PAIRS
#undef ISSUE
}

// ---------------- Kernel 3: final sum ---------------------------------------
__global__ __launch_bounds__(64) void k_reduce(
    const float* __restrict__ loss, float* __restrict__ out)
{
    int lane = threadIdx.x;
    float v = (lane < N) ? loss[lane] : 0.f;
    for (int off = 32; off; off >>= 1) v += __shfl_xor(v, off);
    if (lane == 0) out[0] = v;
}

extern "C" void kernel_launch(void* const* d_in, const int* in_sizes, int n_in,
                              void* d_out, int out_size, void* d_ws, size_t ws_size,
                              hipStream_t stream) {
    const float* x       = (const float*)d_in[0];
    const int*   labels  = (const int*)d_in[1];
    const int*   in_len  = (const int*)d_in[2];
    const int*   lab_len = (const int*)d_in[3];
    float* out  = (float*)d_out;
    float* pp   = (float*)d_ws;                          // TN*ROWF floats
    float* ee   = pp + (size_t)TN * ROWF + 256;          // TN floats
    float* loss = ee + TN;                               // N floats
    // probe scratch (separate region)
    float* ppB   = loss + N;
    float* eeB   = ppB + (size_t)TN * ROWF + 256;
    float* lossB = eeB + TN;

    k_softmax_probs<1><<<TN / 4, 256, 0, stream>>>(x, labels, pp, ee);
    k_ctc_alpha<1><<<2, 1024, 0, stream>>>(pp, ee, labels, in_len, lab_len, loss);
    k_reduce<<<1, 64, 0, stream>>>(loss, out);

    // --- timing probes (scratch only; remove next round) ---
    k_softmax_probs<12><<<TN / 4, 256, 0, stream>>>(x, labels, ppB, eeB);
    k_ctc_alpha<16><<<2, 1024, 0, stream>>>(pp, ee, labels, in_len, lab_len, lossB);
}

// Round 13
// 116.071 us; speedup vs baseline: 18.5470x; 18.5470x over previous
//
#include <hip/hip_runtime.h>

#define LN2 0.6931471805599453f

typedef float f4 __attribute__((ext_vector_type(4)));

constexpr int T = 512, N = 32, C = 4000, S = 64;
constexpr int TN   = T * N;
constexpr int ROWF = 68;          // pp row stride (272B, 16B-aligned)
constexpr int NCH  = 64;          // 8-step chunks
constexpr int JROW = 132;         // floats per j-plane (129 pos padded)
constexpr int WXOFF = 17 * JROW;  // 2244: dense wX[17] after the j-planes
constexpr int CHF  = 2304;        // chunk stride floats = 9216B = 9 DMA loads
constexpr int CTG  = 16;          // generic-fallback chunk (timesteps)

// ---------------- Kernel 1: row-normalized softmax probs (R11) ---------------
__global__ __launch_bounds__(256) void k_softmax_probs(
    const float* __restrict__ x, const int* __restrict__ labels,
    float* __restrict__ pp, float* __restrict__ ee)
{
    int row  = blockIdx.x * 4 + (threadIdx.x >> 6);   // row = t*N + n
    int lane = threadIdx.x & 63;
    const float*  rp  = x + (size_t)row * C;
    const float4* rp4 = reinterpret_cast<const float4*>(rp);

    float m = -INFINITY, s = 0.f;
    #pragma unroll
    for (int k = 0; k < 15; ++k) {                 // 960 of 1000 float4s
        float4 v = rp4[lane + 64 * k];
        float mv = fmaxf(fmaxf(v.x, v.y), fmaxf(v.z, v.w));
        float s4 = __expf(v.x - mv) + __expf(v.y - mv) +
                   __expf(v.z - mv) + __expf(v.w - mv);
        float nm = fmaxf(m, mv);
        s = s * __expf(m - nm) + s4 * __expf(mv - nm);
        m = nm;
    }
    if (lane < 40) {                               // tail 40 float4s
        float4 v = rp4[960 + lane];
        float mv = fmaxf(fmaxf(v.x, v.y), fmaxf(v.z, v.w));
        float s4 = __expf(v.x - mv) + __expf(v.y - mv) +
                   __expf(v.z - mv) + __expf(v.w - mv);
        float nm = fmaxf(m, mv);
        s = s * __expf(m - nm) + s4 * __expf(mv - nm);
        m = nm;
    }
    for (int off = 32; off; off >>= 1) {
        float om = __shfl_xor(m, off), os = __shfl_xor(s, off);
        float nm = fmaxf(m, om);
        s = s * __expf(m - nm) + os * __expf(om - nm);
        m = nm;
    }
    float logZ = m + __logf(s);

    int t = row >> 5, n = row & 31;
    int c  = labels[n * S + lane];
    float zb = rp[0];
    float zl = rp[c];

    float wm = zl;
    for (int off = 32; off; off >>= 1) wm = fmaxf(wm, __shfl_xor(wm, off));
    wm = fmaxf(wm, zb);
    float pm = __expf(wm - logZ);
    int e = (int)(__float_as_uint(pm) >> 23) - 127;

    float* outp = pp + ((size_t)n * T + t) * ROWF;
    outp[1 + lane] = ldexpf(__expf(zl - logZ), -e);
    if (lane == 0) {
        outp[0] = ldexpf(__expf(zb - logZ), -e);
        ee[n * T + t] = (float)e;
    }
}

// ---------------- DPP helpers ------------------------------------------------
__device__ __forceinline__ float dpp_shr1_zero(float x) {
    int r = __builtin_amdgcn_update_dpp(0, __float_as_int(x),
                                        0x138 /*wave_shr:1*/, 0xf, 0xf, false);
    return __int_as_float(r);
}
template <int CTRL>
__device__ __forceinline__ float dpp_max_step(float x) {
    int t = __builtin_amdgcn_update_dpp(__float_as_int(x), __float_as_int(x),
                                        CTRL, 0xf, 0xf, false);
    return fmaxf(x, __int_as_float(t));
}
__device__ __forceinline__ float wave_max_bcast(float x) {
    x = dpp_max_step<0xB1>(x);  x = dpp_max_step<0x4E>(x);
    x = dpp_max_step<0x141>(x); x = dpp_max_step<0x140>(x);
    x = dpp_max_step<0x142>(x); x = dpp_max_step<0x143>(x);
    return __int_as_float(__builtin_amdgcn_readlane(__float_as_int(x), 63));
}

// ---------------- Kernel A: 8-step chunk transfer operators -----------------
// One wave per (n, chunk). Propagates the banded coefficient matrix W[l][j]
// (j = distance to chunk-start position) through the chunk's 8 timesteps.
// Lane i holds rows 2i (w0), 2i+1 (w1); lane 63 also row 128 (wx).
// Chunk c covers timesteps t in [8c, 8c+8) intersect [1, T).
__global__ __launch_bounds__(256) void k_ops(
    const float* __restrict__ pp, const int* __restrict__ labels,
    float* __restrict__ coef)
{
    int unit = blockIdx.x * 4 + (threadIdx.x >> 6);   // 0..2047
    int lane = threadIdx.x & 63;
    int n = unit & 31, c = unit >> 5;

    const int li   = labels[n * S + lane];
    const int lim1 = lane ? labels[n * S + lane - 1] : -1;
    const float skf = (lane > 0 && li != 0 && li != lim1) ? 1.f : 0.f;

    float w0[17], w1[17], wx[17];
    #pragma unroll
    for (int j = 0; j < 17; ++j) { w0[j] = 0.f; w1[j] = 0.f; wx[j] = 0.f; }
    w0[0] = 1.f; w1[0] = 1.f; wx[0] = 1.f;

    const float* base = pp + ((size_t)n * T + 8 * c) * ROWF;
    #pragma unroll
    for (int st = 0; st < 8; ++st) {
        if (!(c == 0 && st == 0)) {                   // t=0 is init, not a step
            float cb = base[st * ROWF];
            float cl = base[st * ROWF + 1 + lane];
            const int jm = (2 * st + 2 < 16) ? 2 * st + 2 : 16;
            float w1m[17], n1[17];
            #pragma unroll
            for (int j = 0; j < 17; ++j) if (j <= jm)
                w1m[j] = dpp_shr1_zero(w1[j]);
            #pragma unroll
            for (int j = 0; j < 17; ++j) if (j <= jm)     // row 128 (blank)
                wx[j] = cb * (wx[j] + (j >= 1 ? w1[j - 1] : 0.f));
            #pragma unroll
            for (int j = 0; j < 17; ++j) if (j <= jm)     // odd row 2i+1
                n1[j] = cl * (w1[j] + (j >= 1 ? w0[j - 1] : 0.f)
                              + skf * (j >= 2 ? w1m[j - 2] : 0.f));
            #pragma unroll
            for (int j = 0; j < 17; ++j) if (j <= jm)     // even row 2i (blank)
                w0[j] = cb * (w0[j] + (j >= 1 ? w1m[j - 1] : 0.f));
            #pragma unroll
            for (int j = 0; j < 17; ++j) if (j <= jm)
                w1[j] = n1[j];
        }
    }

    // store j-major: [j][pos] (pos pad 132), wX dense at WXOFF
    float* cbase = coef + ((size_t)n * NCH + c) * CHF;
    #pragma unroll
    for (int j = 0; j < 17; ++j) {
        float2 v; v.x = w0[j]; v.y = w1[j];
        *reinterpret_cast<float2*>(cbase + j * JROW + 2 * lane) = v;
    }
    if (lane == 63) {
        #pragma unroll
        for (int j = 0; j < 17; ++j) cbase[WXOFF + j] = wx[j];
    }
}

// ---------------- Kernel B: alpha recursion via chunk operators -------------
// One wave per n. Per chunk: DMA-staged operator (2 ahead), 16 shuffles for
// the alpha neighborhood, 3 banded dots (17 FMA each), lag-2 deadbeat renorm.
__global__ __launch_bounds__(64) void k_ctc_alpha(
    const float* __restrict__ pp, const float* __restrict__ coef,
    const float* __restrict__ ee, const int* __restrict__ labels,
    const int* __restrict__ input_len, const int* __restrict__ label_len,
    float* __restrict__ loss_out)
{
    __shared__ __align__(16) float ldsH[2][CHF];         // 18.4 KB (operators)
    __shared__ __align__(16) float ldsG[2][CTG][ROWF];   // 8.7 KB (fallback)
    const int n = blockIdx.x, lane = threadIdx.x;
    const int Tin = input_len[n], Sl = label_len[n];
    const float* bp = pp + (size_t)n * T * ROWF;
    const float* cf = coef + (size_t)n * NCH * CHF;

    const int li   = labels[n * S + lane];
    const int lim1 = lane ? labels[n * S + lane - 1] : -1;
    const float skf = (lane > 0 && li != 0 && li != lim1) ? 1.f : 0.f;

    float a0 = 0.f, a1 = 0.f, aX = 0.f;
    int SH = 0, kA = 0;
    float gs = 0.f;

#define ISSUE(cc) do {                                                        \
    const float* src_ = cf + (size_t)(cc) * CHF;                              \
    float* dst_ = &ldsH[(cc) & 1][0];                                         \
    _Pragma("unroll")                                                         \
    for (int i_ = 0; i_ < 9; ++i_)                                            \
        __builtin_amdgcn_global_load_lds(src_ + i_ * 256 + lane * 4,          \
                                         dst_ + i_ * 256, 16, 0, 0);          \
    } while (0)

    if (Tin == T) {
        // ---------------- hot path: scan over 64 chunk operators ------------
        float p00 = bp[0], p01 = bp[1];                  // t=0 init values
        asm volatile("s_waitcnt vmcnt(0)" ::: "memory"); // drain plain loads
        __builtin_amdgcn_sched_barrier(0);
        ISSUE(0); ISSUE(1);

        a0 = (lane == 0) ? p00 : 0.f;
        a1 = (lane == 0 && Sl > 0) ? p01 : 0.f;
        gs = fmaxf(a0, a1);                              // kickstart snapshot

        for (int c = 0; c < NCH; ++c) {
            if (c < NCH - 1) { asm volatile("s_waitcnt vmcnt(9)" ::: "memory"); }
            else             { asm volatile("s_waitcnt vmcnt(0)" ::: "memory"); }
            __builtin_amdgcn_sched_barrier(0);
            const float* ldsb = &ldsH[c & 1][0];

            // apply pending renorm (lag-2 deadbeat, anchor 105 -- R11 proven)
            a0 = ldexpf(a0, kA); a1 = ldexpf(a1, kA); aX = ldexpf(aX, kA);
            SH += kA;
            float gnow = fmaxf(fmaxf(a0, a1), aX);

            // operator rows for this lane's positions + broadcast wX
            float2 W[17];
            #pragma unroll
            for (int j = 0; j < 17; ++j)
                W[j] = *reinterpret_cast<const float2*>(&ldsb[j * JROW + 2 * lane]);
            f4 WX[5];
            #pragma unroll
            for (int q = 0; q < 5; ++q)
                WX[q] = *reinterpret_cast<const f4*>(&ldsb[WXOFF + 4 * q]);

            // alpha neighborhood: shifted copies s=1..8 (0 beyond pos 0)
            float A0[9], A1[9];
            A0[0] = a0; A1[0] = a1;
            #pragma unroll
            for (int s2 = 1; s2 <= 8; ++s2) {
                float u0 = __shfl_up(a0, s2), u1 = __shfl_up(a1, s2);
                A0[s2] = (lane >= s2) ? u0 : 0.f;
                A1[s2] = (lane >= s2) ? u1 : 0.f;
            }

            // banded dots (2 partials each for tree depth)
            float x0a = 0.f, x0b = 0.f, x1a = 0.f, x1b = 0.f;
            float xXa = 0.f, xXb = 0.f;
            #pragma unroll
            for (int j = 0; j < 17; ++j) {
                float av0 = (j & 1) ? A1[(j + 1) >> 1] : A0[j >> 1];
                float av1 = (j & 1) ? A0[(j - 1) >> 1] : A1[j >> 1];
                float avX = (j == 0) ? aX
                          : ((j & 1) ? A1[(j - 1) >> 1] : A0[(j >> 1) - 1]);
                float wxj = WX[j >> 2][j & 3];
                if (j & 1) {
                    x0b = fmaf(W[j].x, av0, x0b);
                    x1b = fmaf(W[j].y, av1, x1b);
                    xXb = fmaf(wxj,    avX, xXb);
                } else {
                    x0a = fmaf(W[j].x, av0, x0a);
                    x1a = fmaf(W[j].y, av1, x1a);
                    xXa = fmaf(wxj,    avX, xXa);
                }
            }
            a0 = x0a + x0b;
            a1 = x1a + x1b;
            aX = (lane == 63) ? (xXa + xXb) : 0.f;

            // off-chain max tree on the lag snapshot; deadbeat kA update
            gs = dpp_max_step<0xB1>(gs);  gs = dpp_max_step<0x4E>(gs);
            gs = dpp_max_step<0x141>(gs); gs = dpp_max_step<0x140>(gs);
            gs = dpp_max_step<0x142>(gs); gs = dpp_max_step<0x143>(gs);
            {
                unsigned b_ = (unsigned)__builtin_amdgcn_readlane(
                                  __float_as_int(gs), 63);
                int e_ = (int)(b_ >> 23) - 127;
                kA = (b_ == 0u) ? 0 : (105 - e_ - kA);
            }
            gs = gnow;

            if (c + 2 < NCH) {
                __builtin_amdgcn_sched_barrier(0);
                ISSUE(c + 2);
            }
        }
    } else {
        // ---------------- generic fallback: per-step from pp (R11) ----------
#define ISSUEG(cc) do {                                                       \
    const float* cp_ = bp + (size_t)(cc) * CTG * ROWF;                        \
    if (lane < 17) {                                                          \
        _Pragma("unroll")                                                     \
        for (int d_ = 0; d_ < CTG; ++d_)                                      \
            __builtin_amdgcn_global_load_lds(cp_ + (size_t)d_ * ROWF + lane * 4, \
                                             &ldsG[(cc) & 1][d_][0], 16, 0, 0);\
    } } while (0)
#define GSTEP(cc, dd) do {                                                    \
    float cb_ = ldsG[(cc) & 1][dd][0];                                        \
    float cl_ = ldsG[(cc) & 1][dd][1 + lane];                                 \
    float p1_ = dpp_shr1_zero(a1);                                            \
    float na0_ = (a0 + p1_) * cb_;                                            \
    float na1_ = fmaf(skf, p1_, a0 + a1) * cl_;                               \
    float naX_ = (aX + a1) * cb_;                                             \
    int t_ = (cc) * CTG + (dd);                                               \
    bool act_ = (unsigned)(t_ - 1) < (unsigned)(Tin - 1);                     \
    a0 = act_ ? na0_ : a0;                                                    \
    a1 = act_ ? na1_ : a1;                                                    \
    aX = act_ ? naX_ : aX;                                                    \
    if (((dd) & 3) == 3) {                                                    \
        float g_ = wave_max_bcast(fmaxf(a0, fmaxf(a1, aX)));                  \
        unsigned b_ = __float_as_uint(g_);                                    \
        int k_ = (b_ == 0u) ? 0 : (100 - ((int)(b_ >> 23) - 127));            \
        a0 = ldexpf(a0, k_); a1 = ldexpf(a1, k_); aX = ldexpf(aX, k_);        \
        SH += k_;                                                             \
    }                                                                         \
} while (0)
        asm volatile("s_waitcnt vmcnt(0)" ::: "memory");
        __builtin_amdgcn_sched_barrier(0);
        ISSUEG(0); ISSUEG(1);
        asm volatile("s_waitcnt vmcnt(16)" ::: "memory");
        __builtin_amdgcn_sched_barrier(0);
        a0 = (lane == 0) ? ldsG[0][0][0] : 0.f;
        a1 = (lane == 0 && Sl > 0) ? ldsG[0][0][1] : 0.f;
        #pragma unroll
        for (int d = 1; d < CTG; ++d) GSTEP(0, d);
        __builtin_amdgcn_sched_barrier(0);
        ISSUEG(2);
        for (int c = 1; c < T / CTG; ++c) {
            if (c < T / CTG - 1) { asm volatile("s_waitcnt vmcnt(16)" ::: "memory"); }
            else                 { asm volatile("s_waitcnt vmcnt(0)"  ::: "memory"); }
            __builtin_amdgcn_sched_barrier(0);
            #pragma unroll
            for (int d = 0; d < CTG; ++d) GSTEP(c, d);
            if (c + 2 < T / CTG) {
                __builtin_amdgcn_sched_barrier(0);
                ISSUEG(c + 2);
            }
        }
#undef GSTEP
#undef ISSUEG
    }
#undef ISSUE

    // row-scale compensation: Sigma e_t over t < Tin
    float se = 0.f;
    #pragma unroll
    for (int j = 0; j < 8; ++j) {
        int idx = lane + 64 * j;
        float ev = ee[n * T + idx];
        se += (idx < Tin) ? ev : 0.f;
    }
    for (int off = 32; off; off >>= 1) se += __shfl_xor(se, off);

    // loss_n = -log(alpha[2*Sl] + alpha[2*Sl-1]), rescaled
    float a_last = (Sl >= S) ? __shfl(aX, 63) : __shfl(a0, Sl);
    float a_prev_raw = __shfl(a1, (Sl > 0) ? (Sl - 1) : 0);
    float a_prev = (Sl > 0) ? a_prev_raw : 0.f;
    if (lane == 0) {
        float sum  = a_last + a_prev;
        float ll2  = log2f(sum) - (float)SH + se;
        float loss = -ll2 * LN2;
        if (!(loss < 5e29f)) loss = 0.f;               // zero_infinity (+NaN)
        loss_out[n] = loss;
    }
}

// ---------------- Kernel 3: final sum ---------------------------------------
__global__ __launch_bounds__(64) void k_reduce(
    const float* __restrict__ loss, float* __restrict__ out)
{
    int lane = threadIdx.x;
    float v = (lane < N) ? loss[lane] : 0.f;
    for (int off = 32; off; off >>= 1) v += __shfl_xor(v, off);
    if (lane == 0) out[0] = v;
}

extern "C" void kernel_launch(void* const* d_in, const int* in_sizes, int n_in,
                              void* d_out, int out_size, void* d_ws, size_t ws_size,
                              hipStream_t stream) {
    const float* x       = (const float*)d_in[0];
    const int*   labels  = (const int*)d_in[1];
    const int*   in_len  = (const int*)d_in[2];
    const int*   lab_len = (const int*)d_in[3];
    float* out  = (float*)d_out;
    float* pp   = (float*)d_ws;                          // TN*ROWF floats
    float* ee   = pp + (size_t)TN * ROWF + 256;          // TN floats
    float* loss = ee + TN;                               // N floats
    float* coef = loss + N + 64;                         // N*NCH*CHF floats (~19MB)

    k_softmax_probs<<<TN / 4, 256, 0, stream>>>(x, labels, pp, ee);
    k_ops<<<N * NCH / 4, 256, 0, stream>>>(pp, labels, coef);
    k_ctc_alpha<<<N, 64, 0, stream>>>(pp, coef, ee, labels, in_len, lab_len, loss);
    k_reduce<<<1, 64, 0, stream>>>(loss, out);
}

// Round 14
// 77.567 us; speedup vs baseline: 27.7539x; 1.4964x over previous
//
#include <hip/hip_runtime.h>

#define LN2 0.6931471805599453f

constexpr int T = 512, N = 32, C = 4000, S = 64;
constexpr int TN   = T * N;
constexpr int ROWF = 68;          // pp row stride (272B, 16B-aligned)
constexpr int CT   = 16;          // timesteps per LDS chunk
constexpr int NCF  = 16;          // forward chunks (t in [0,256))
constexpr int NCB  = 16;          // backward chunks (t in [256,512))
constexpr int NCG  = 32;          // generic-path chunks (full T)

// ---------------- Kernel 1: row-normalized softmax probs ---------------------
__global__ __launch_bounds__(256) void k_softmax_probs(
    const float* __restrict__ x, const int* __restrict__ labels,
    float* __restrict__ pp, float* __restrict__ ee)
{
    int row  = blockIdx.x * 4 + (threadIdx.x >> 6);   // row = t*N + n
    int lane = threadIdx.x & 63;
    const float*  rp  = x + (size_t)row * C;
    const float4* rp4 = reinterpret_cast<const float4*>(rp);

    float m = -INFINITY, s = 0.f;
    #pragma unroll
    for (int k = 0; k < 15; ++k) {                 // 960 of 1000 float4s
        float4 v = rp4[lane + 64 * k];
        float mv = fmaxf(fmaxf(v.x, v.y), fmaxf(v.z, v.w));
        float s4 = __expf(v.x - mv) + __expf(v.y - mv) +
                   __expf(v.z - mv) + __expf(v.w - mv);
        float nm = fmaxf(m, mv);
        s = s * __expf(m - nm) + s4 * __expf(mv - nm);
        m = nm;
    }
    if (lane < 40) {                               // tail 40 float4s
        float4 v = rp4[960 + lane];
        float mv = fmaxf(fmaxf(v.x, v.y), fmaxf(v.z, v.w));
        float s4 = __expf(v.x - mv) + __expf(v.y - mv) +
                   __expf(v.z - mv) + __expf(v.w - mv);
        float nm = fmaxf(m, mv);
        s = s * __expf(m - nm) + s4 * __expf(mv - nm);
        m = nm;
    }
    for (int off = 32; off; off >>= 1) {
        float om = __shfl_xor(m, off), os = __shfl_xor(s, off);
        float nm = fmaxf(m, om);
        s = s * __expf(m - nm) + os * __expf(om - nm);
        m = nm;
    }
    float logZ = m + __logf(s);

    int t = row >> 5, n = row & 31;
    int c  = labels[n * S + lane];
    float zb = rp[0];
    float zl = rp[c];

    float wm = zl;
    for (int off = 32; off; off >>= 1) wm = fmaxf(wm, __shfl_xor(wm, off));
    wm = fmaxf(wm, zb);
    float pm = __expf(wm - logZ);
    int e = (int)(__float_as_uint(pm) >> 23) - 127;

    float* outp = pp + ((size_t)n * T + t) * ROWF;
    outp[1 + lane] = ldexpf(__expf(zl - logZ), -e);
    if (lane == 0) {
        outp[0] = ldexpf(__expf(zb - logZ), -e);
        ee[n * T + t] = (float)e;
    }
}

// ---------------- DPP helpers ------------------------------------------------
__device__ __forceinline__ float dpp_shr1_zero(float x) {   // from lane-1; lane0<-0
    int r = __builtin_amdgcn_update_dpp(0, __float_as_int(x),
                                        0x138 /*wave_shr:1*/, 0xf, 0xf, false);
    return __int_as_float(r);
}
__device__ __forceinline__ float dpp_shl1_zero(float x) {   // from lane+1; lane63<-0
    int r = __builtin_amdgcn_update_dpp(0, __float_as_int(x),
                                        0x130 /*wave_shl:1*/, 0xf, 0xf, false);
    return __int_as_float(r);
}
template <int CTRL>
__device__ __forceinline__ float dpp_max_step(float x) {
    int t = __builtin_amdgcn_update_dpp(__float_as_int(x), __float_as_int(x),
                                        CTRL, 0xf, 0xf, false);
    return fmaxf(x, __int_as_float(t));
}
__device__ __forceinline__ float wave_max_bcast(float x) {
    x = dpp_max_step<0xB1>(x);  x = dpp_max_step<0x4E>(x);
    x = dpp_max_step<0x141>(x); x = dpp_max_step<0x140>(x);
    x = dpp_max_step<0x142>(x); x = dpp_max_step<0x143>(x);
    return __int_as_float(__builtin_amdgcn_readlane(__float_as_int(x), 63));
}

// ---------------- Kernel 2: bidirectional alpha/gamma, 2 waves per n --------
// Wave 0: forward alpha t=0..255 (R11 pair-composed hot path, halved span).
// Wave 1: backward gamma t=511..255 (single steps, shl-mirrored).
// Join: P = sum_l alpha_255[l] * gamma_255[l] via LDS + barrier.
__global__ __launch_bounds__(128) void k_ctc_alpha(
    const float* __restrict__ pp, const float* __restrict__ ee,
    const int* __restrict__ labels,
    const int* __restrict__ input_len, const int* __restrict__ label_len,
    float* __restrict__ loss_out)
{
    __shared__ __align__(16) float ldsF[2][CT][ROWF];   // 8.7 KB forward
    __shared__ __align__(16) float ldsB[2][CT][ROWF];   // 8.7 KB backward
    __shared__ float gj[132];                           // join: gamma, SH_b
    const int n = blockIdx.x;
    const int wid = threadIdx.x >> 6, lane = threadIdx.x & 63;
    const int Tin = input_len[n], Sl = label_len[n];
    const float* bp = pp + (size_t)n * T * ROWF;
    const bool hot = (Tin == T);

    const int li   = labels[n * S + lane];
    const int lim1 = lane ? labels[n * S + lane - 1] : -1;
    const float skf  = (lane > 0 && li != 0 && li != lim1) ? 1.f : 0.f;
    const float skUf = dpp_shr1_zero(skf);
    const float skk  = skf * skUf;
    const float skD  = dpp_shl1_zero(skf);              // skip flag of lane+1

    asm volatile("s_waitcnt vmcnt(0)" ::: "memory");    // exact DMA counting
    __builtin_amdgcn_sched_barrier(0);

    float a0 = 0.f, a1 = 0.f, aX = 0.f;                 // wave0 result state
    int SH = 0;

#define ISSUE_F(cc) do {                                                      \
    const float* cp_ = bp + (size_t)(cc) * CT * ROWF;                         \
    if (lane < 17) {                                                          \
        _Pragma("unroll")                                                     \
        for (int d_ = 0; d_ < CT; ++d_)                                       \
            __builtin_amdgcn_global_load_lds(cp_ + (size_t)d_ * ROWF + lane * 4, \
                                             &ldsF[(cc) & 1][d_][0], 16, 0, 0);\
    } } while (0)
#define ISSUE_B(cc) do {                                                      \
    const float* cp_ = bp + (size_t)(496 - 16 * (cc)) * ROWF;                 \
    if (lane < 17) {                                                          \
        _Pragma("unroll")                                                     \
        for (int d_ = 0; d_ < CT; ++d_)                                       \
            __builtin_amdgcn_global_load_lds(cp_ + (size_t)d_ * ROWF + lane * 4, \
                                             &ldsB[(cc) & 1][d_][0], 16, 0, 0);\
    } } while (0)

// ---- forward pair step (R11 verbatim, ldsF) ----
#define PAIRS(B, D) do {                                                      \
    const float* R0_ = &ldsF[B][D][0];                                        \
    const float* R1_ = &ldsF[B][(D) + 1][0];                                  \
    float cb1 = R0_[0], cl1 = R0_[1 + lane];                                  \
    float cb2 = R1_[0], cl2 = R1_[1 + lane];                                  \
    float clU = dpp_shr1_zero(cl1);                                           \
    float W   = clU * cl2;                                                    \
    float A   = cb1 * cb2;                                                    \
    float B_  = clU * cb2;                                                    \
    float Cc  = A + B_;                                                       \
    float D_  = skUf * B_;                                                    \
    float s1  = cb1 + cl1;                                                    \
    float E   = s1 * cl2;                                                     \
    float F   = cl1 * cl2;                                                    \
    float G   = skf * W;                                                      \
    float H   = fmaf(skf, F + W, cb1 * cl2);                                  \
    float I   = skk * W;                                                      \
    float Y0  = cl1 * cb2;                                                    \
    float Y1  = s1 * cb2;                                                     \
    float Y2  = skf * Y0;                                                     \
    float p1  = dpp_shr1_zero(a1);                                            \
    float p0  = dpp_shr1_zero(a0);                                            \
    float p2  = dpp_shr1_zero(p1);                                            \
    float n0  = fmaf(p0, B_, a0 * A) + fmaf(p2, D_, p1 * Cc);                 \
    float n1  = fmaf(a1, F, a0 * E) + fmaf(p2, I, fmaf(p1, H, p0 * G));       \
    float nX  = fmaf(a1, Y1, aX * A) + fmaf(p1, Y2, a0 * Y0);                 \
    a0 = n0; a1 = n1; aX = nX;                                                \
} while (0)

#define WINDOW4(B, D0) do {                                                   \
    a0 = ldexpf(a0, kA); a1 = ldexpf(a1, kA); aX = ldexpf(aX, kA);            \
    SH += kA;                                                                 \
    float gnow_ = fmaxf(fmaxf(a0, a1), aX);                                   \
    PAIRS(B, D0);                                                             \
    gs = dpp_max_step<0xB1>(gs);  gs = dpp_max_step<0x4E>(gs);                \
    PAIRS(B, (D0) + 2);                                                       \
    gs = dpp_max_step<0x141>(gs); gs = dpp_max_step<0x140>(gs);               \
    PAIRS(B, (D0) + 4);                                                       \
    gs = dpp_max_step<0x142>(gs); gs = dpp_max_step<0x143>(gs);               \
    PAIRS(B, (D0) + 6);                                                       \
    {   unsigned b_ = (unsigned)__builtin_amdgcn_readlane(__float_as_int(gs), 63); \
        int e_ = (int)(b_ >> 23) - 127;                                       \
        kA = (b_ == 0u) ? 0 : (105 - e_ - kA);                                \
    }                                                                         \
    gs = gnow_;                                                               \
} while (0)

// ---- backward single step (row D of ldsB chunk B): gamma_t from gamma_{t+1} --
#define BSTEP(B, D) do {                                                      \
    const float* R_ = &ldsB[B][D][0];                                         \
    float cb_ = R_[0], cl_ = R_[1 + lane];                                    \
    float cD_ = dpp_shl1_zero(cl_);              /* cl of lane+1 */           \
    float d1_ = dpp_shl1_zero(g1);               /* gamma[2i+3] */            \
    float d0s_ = dpp_shl1_zero(g0);              /* gamma[2i+2] */            \
    float d0_ = (lane == 63) ? gX : d0s_;        /* lane63: gamma[128] */     \
    float t1_ = skD * cD_;                                                    \
    float cg_ = cl_ * g1;                                                     \
    float ng0 = fmaf(cb_, g0, cg_);                                           \
    float ng1 = fmaf(t1_, d1_, fmaf(cb_, d0_, cg_));                          \
    float ngX = cb_ * gX;                                                     \
    g0 = ng0; g1 = ng1; gX = ngX;                                             \
} while (0)

// 8 backward steps (rows D0+7 .. D0 descending) + lag-2 off-chain renorm
#define BWIN(B, D0) do {                                                      \
    g0 = ldexpf(g0, kB); g1 = ldexpf(g1, kB); gX = ldexpf(gX, kB);            \
    SHb += kB;                                                                \
    float gnow_ = fmaxf(fmaxf(g0, g1), gX);                                   \
    BSTEP(B, (D0) + 7); BSTEP(B, (D0) + 6);                                   \
    gsb = dpp_max_step<0xB1>(gsb);  gsb = dpp_max_step<0x4E>(gsb);            \
    BSTEP(B, (D0) + 5); BSTEP(B, (D0) + 4);                                   \
    gsb = dpp_max_step<0x141>(gsb); gsb = dpp_max_step<0x140>(gsb);           \
    BSTEP(B, (D0) + 3); BSTEP(B, (D0) + 2);                                   \
    gsb = dpp_max_step<0x142>(gsb); gsb = dpp_max_step<0x143>(gsb);           \
    BSTEP(B, (D0) + 1); BSTEP(B, (D0));                                       \
    {   unsigned b_ = (unsigned)__builtin_amdgcn_readlane(__float_as_int(gsb), 63); \
        int e_ = (int)(b_ >> 23) - 127;                                       \
        kB = (b_ == 0u) ? 0 : (100 - e_ - kB);                                \
    }                                                                         \
    gsb = gnow_;                                                              \
} while (0)

    if (wid == 0) {
        if (hot) {
            // ---------- forward hot: t = 0..255 ----------
            int kA = 0; float gs = 0.f;
            ISSUE_F(0); ISSUE_F(1);
            asm volatile("s_waitcnt vmcnt(16)" ::: "memory");
            __builtin_amdgcn_sched_barrier(0);
            a0 = (lane == 0) ? ldsF[0][0][0] : 0.f;
            a1 = (lane == 0 && Sl > 0) ? ldsF[0][0][1] : 0.f;
            {   // t = 1 single step
                float cb = ldsF[0][1][0], cl = ldsF[0][1][1 + lane];
                float p1 = dpp_shr1_zero(a1);
                float n0 = (a0 + p1) * cb;
                float n1 = fmaf(skf, p1, a0 + a1) * cl;
                float nX = (aX + a1) * cb;
                a0 = n0; a1 = n1; aX = nX;
            }
            PAIRS(0, 2); PAIRS(0, 4); PAIRS(0, 6);       // t = 2..7
            {   float g = wave_max_bcast(fmaxf(fmaxf(a0, a1), aX));
                unsigned b = __float_as_uint(g);
                int k0 = (b == 0u) ? 0 : (105 - ((int)(b >> 23) - 127));
                a0 = ldexpf(a0, k0); a1 = ldexpf(a1, k0); aX = ldexpf(aX, k0);
                SH += k0; kA = 0;
                gs = fmaxf(fmaxf(a0, a1), aX);
            }
            WINDOW4(0, 8);                               // t = 8..15
            __builtin_amdgcn_sched_barrier(0);
            ISSUE_F(2);
            for (int c = 1; c < NCF; ++c) {
                if (c < NCF - 1) { asm volatile("s_waitcnt vmcnt(16)" ::: "memory"); }
                else             { asm volatile("s_waitcnt vmcnt(0)"  ::: "memory"); }
                __builtin_amdgcn_sched_barrier(0);
                int buf = c & 1;
                WINDOW4(buf, 0);
                WINDOW4(buf, 8);
                if (c + 2 < NCF) {
                    __builtin_amdgcn_sched_barrier(0);
                    ISSUE_F(c + 2);
                }
            }
        } else {
            // ---------- generic fallback: full T, per-step (R11) ----------
#define GSTEP(cc, dd) do {                                                    \
    float cb_ = ldsF[(cc) & 1][dd][0];                                        \
    float cl_ = ldsF[(cc) & 1][dd][1 + lane];                                 \
    float p1_ = dpp_shr1_zero(a1);                                            \
    float na0_ = (a0 + p1_) * cb_;                                            \
    float na1_ = fmaf(skf, p1_, a0 + a1) * cl_;                               \
    float naX_ = (aX + a1) * cb_;                                             \
    int t_ = (cc) * CT + (dd);                                                \
    bool act_ = (unsigned)(t_ - 1) < (unsigned)(Tin - 1);                     \
    a0 = act_ ? na0_ : a0;                                                    \
    a1 = act_ ? na1_ : a1;                                                    \
    aX = act_ ? naX_ : aX;                                                    \
    if (((dd) & 3) == 3) {                                                    \
        float g_ = wave_max_bcast(fmaxf(a0, fmaxf(a1, aX)));                  \
        unsigned b_ = __float_as_uint(g_);                                    \
        int k_ = (b_ == 0u) ? 0 : (100 - ((int)(b_ >> 23) - 127));            \
        a0 = ldexpf(a0, k_); a1 = ldexpf(a1, k_); aX = ldexpf(aX, k_);        \
        SH += k_;                                                             \
    }                                                                         \
} while (0)
            ISSUE_F(0); ISSUE_F(1);
            asm volatile("s_waitcnt vmcnt(16)" ::: "memory");
            __builtin_amdgcn_sched_barrier(0);
            a0 = (lane == 0) ? ldsF[0][0][0] : 0.f;
            a1 = (lane == 0 && Sl > 0) ? ldsF[0][0][1] : 0.f;
            #pragma unroll
            for (int d = 1; d < CT; ++d) GSTEP(0, d);
            __builtin_amdgcn_sched_barrier(0);
            ISSUE_F(2);
            for (int c = 1; c < NCG; ++c) {
                if (c < NCG - 1) { asm volatile("s_waitcnt vmcnt(16)" ::: "memory"); }
                else             { asm volatile("s_waitcnt vmcnt(0)"  ::: "memory"); }
                __builtin_amdgcn_sched_barrier(0);
                #pragma unroll
                for (int d = 0; d < CT; ++d) GSTEP(c, d);
                if (c + 2 < NCG) {
                    __builtin_amdgcn_sched_barrier(0);
                    ISSUE_F(c + 2);
                }
            }
#undef GSTEP
        }
    } else if (hot) {
        // ---------- backward hot: gamma_511 init, steps down to gamma_255 ----
        float g0 = (lane == Sl) ? 1.f : 0.f;             // l = 2*Sl (Sl<=63)
        float g1 = (Sl > 0 && lane == Sl - 1) ? 1.f : 0.f;   // l = 2*Sl-1
        float gX = (Sl >= S && lane == 63) ? 1.f : 0.f;  // l = 128 when Sl=64
        int SHb = 0, kB = 0;
        float gsb = fmaxf(fmaxf(g0, g1), gX);

        ISSUE_B(0); ISSUE_B(1);
        for (int c = 0; c < NCB; ++c) {
            if (c < NCB - 1) { asm volatile("s_waitcnt vmcnt(16)" ::: "memory"); }
            else             { asm volatile("s_waitcnt vmcnt(0)"  ::: "memory"); }
            __builtin_amdgcn_sched_barrier(0);
            int buf = c & 1;
            BWIN(buf, 8);                                // rows 15..8
            BWIN(buf, 0);                                // rows 7..0
            if (c + 2 < NCB) {
                __builtin_amdgcn_sched_barrier(0);
                ISSUE_B(c + 2);
            }
        }
        // publish gamma_255 (exact 2^-120 shift) + SHb
        gj[2 * lane]     = ldexpf(g0, -120);
        gj[2 * lane + 1] = ldexpf(g1, -120);
        if (lane == 63) {
            gj[128] = ldexpf(gX, -120);
            gj[130] = (float)SHb;
        }
    }

    __syncthreads();
    if (wid != 0) return;

    // ---------------- epilogue (wave 0) ----------------
    float se = 0.f;
    #pragma unroll
    for (int j = 0; j < 8; ++j) {
        int idx = lane + 64 * j;
        float ev = ee[n * T + idx];
        se += (idx < Tin) ? ev : 0.f;
    }
    for (int off = 32; off; off >>= 1) se += __shfl_xor(se, off);

    if (hot) {
        // P = sum_l alpha_255[l] * gamma_255[l]
        float term = a0 * gj[2 * lane] + a1 * gj[2 * lane + 1];
        if (lane == 63) term = fmaf(aX, gj[128], term);
        for (int off = 32; off; off >>= 1) term += __shfl_xor(term, off);
        if (lane == 0) {
            float SHb = gj[130];
            float ll2  = log2f(term) - (float)SH - SHb + 120.f + se;
            float loss = -ll2 * LN2;
            if (!(loss < 5e29f)) loss = 0.f;            // zero_infinity (+NaN)
            loss_out[n] = loss;
        }
    } else {
        float a_last = (Sl >= S) ? __shfl(aX, 63) : __shfl(a0, Sl);
        float a_prev_raw = __shfl(a1, (Sl > 0) ? (Sl - 1) : 0);
        float a_prev = (Sl > 0) ? a_prev_raw : 0.f;
        if (lane == 0) {
            float sum  = a_last + a_prev;
            float ll2  = log2f(sum) - (float)SH + se;
            float loss = -ll2 * LN2;
            if (!(loss < 5e29f)) loss = 0.f;
            loss_out[n] = loss;
        }
    }
#undef BWIN
#undef BSTEP
#undef WINDOW4
#undef PAIRS
#undef ISSUE_F
#undef ISSUE_B
}

// ---------------- Kernel 3: final sum ---------------------------------------
__global__ __launch_bounds__(64) void k_reduce(
    const float* __restrict__ loss, float* __restrict__ out)
{
    int lane = threadIdx.x;
    float v = (lane < N) ? loss[lane] : 0.f;
    for (int off = 32; off; off >>= 1) v += __shfl_xor(v, off);
    if (lane == 0) out[0] = v;
}

extern "C" void kernel_launch(void* const* d_in, const int* in_sizes, int n_in,
                              void* d_out, int out_size, void* d_ws, size_t ws_size,
                              hipStream_t stream) {
    const float* x       = (const float*)d_in[0];
    const int*   labels  = (const int*)d_in[1];
    const int*   in_len  = (const int*)d_in[2];
    const int*   lab_len = (const int*)d_in[3];
    float* out  = (float*)d_out;
    float* pp   = (float*)d_ws;                          // TN*ROWF floats
    float* ee   = pp + (size_t)TN * ROWF + 256;          // TN floats
    float* loss = ee + TN;                               // N floats

    k_softmax_probs<<<TN / 4, 256, 0, stream>>>(x, labels, pp, ee);
    k_ctc_alpha<<<N, 128, 0, stream>>>(pp, ee, labels, in_len, lab_len, loss);
    k_reduce<<<1, 64, 0, stream>>>(loss, out);
}